// Round 7
// baseline (831.574 us; speedup 1.0000x reference)
//
#include <hip/hip_runtime.h>
#include <math.h>

#define BB 4
#define CC 256
#define NN 4096

using half8 = __attribute__((ext_vector_type(8))) _Float16;
using f32x4 = __attribute__((ext_vector_type(4))) float;

__device__ __forceinline__ unsigned short f2h(float f) {
  _Float16 h = (_Float16)f;   // RNE
  return __builtin_bit_cast(unsigned short, h);
}

// XOR bank swizzle at 16B-chunk granularity (row-aligned layouts)
__device__ __forceinline__ int kt_off(int r, int chunk) {   // K view: 64 rows x 512B, short idx
  return r * 256 + (((chunk & 24) | ((chunk ^ r) & 7)) << 3);
}
__device__ __forceinline__ int vt_off(int r, int chunk) {   // V view: 256 rows x 128B, short idx
  return r * 64 + (((chunk ^ r) & 7) << 3);
}

// ---------------- transpose: x (B,C,N) f32 -> Xt (B,N,C) fp16 ----------------
__global__ __launch_bounds__(256) void k_transpose(const float* __restrict__ x,
                                                   unsigned short* __restrict__ Xt) {
  __shared__ float tile[64][65];
  int b = blockIdx.z, c0 = blockIdx.y * 64, n0 = blockIdx.x * 64;
  int t = threadIdx.x;
  const float* xp = x + ((size_t)b * CC + c0) * NN + n0;
#pragma unroll
  for (int p = 0; p < 4; ++p) {
    int c = p * 16 + (t >> 4);
    int j = (t & 15) * 4;
    float4 v = *(const float4*)(xp + (size_t)c * NN + j);
    tile[c][j] = v.x; tile[c][j + 1] = v.y; tile[c][j + 2] = v.z; tile[c][j + 3] = v.w;
  }
  __syncthreads();
  unsigned short* xtp = Xt + ((size_t)b * NN + n0) * CC + c0;
#pragma unroll
  for (int p = 0; p < 2; ++p) {
    int n = p * 32 + (t >> 3);
    int cb = (t & 7) * 8;
    union { unsigned short u[8]; uint4 v; } tmp;
#pragma unroll
    for (int i = 0; i < 8; ++i) tmp.u[i] = f2h(tile[cb + i][n]);
    *(uint4*)(xtp + (size_t)n * CC + cb) = tmp.v;
  }
}

// ---------------- projections ----------------
__global__ __launch_bounds__(256, 1) void k_proj(const unsigned short* __restrict__ Xt,
    const float* __restrict__ Wq, const float* __restrict__ bq,
    const float* __restrict__ Wk, const float* __restrict__ bk,
    const float* __restrict__ Wv, const float* __restrict__ bv,
    unsigned short* __restrict__ Q, unsigned short* __restrict__ K,
    unsigned short* __restrict__ V) {
  __shared__ union {
    struct { unsigned short xa[128][72]; unsigned short wb[256][72]; } s;
    unsigned short qo[128][264];
    unsigned short vo[256][136];
  } u;
  int proj = blockIdx.z;
  const float* W    = proj == 0 ? Wq : (proj == 1 ? Wk : Wv);
  const float* bias = proj == 0 ? bq : (proj == 1 ? bk : bv);
  int b = blockIdx.y, n0 = blockIdx.x * 128;
  int t = threadIdx.x, w = t >> 6, lane = t & 63, l15 = lane & 15, quad = lane >> 4;

  f32x4 z = {0.f, 0.f, 0.f, 0.f};
  f32x4 acc[2][16];
#pragma unroll
  for (int i = 0; i < 2; ++i)
#pragma unroll
    for (int j = 0; j < 16; ++j) acc[i][j] = z;

  for (int ks = 0; ks < 4; ++ks) {
    __syncthreads();
#pragma unroll
    for (int p = 0; p < 4; ++p) {
      int r = p * 32 + (t >> 3);
      *(uint4*)&u.s.xa[r][(t & 7) * 8] =
        *(const uint4*)(Xt + ((size_t)b * NN + n0 + r) * CC + ks * 64 + (t & 7) * 8);
    }
#pragma unroll
    for (int p = 0; p < 16; ++p) {
      int r = p * 16 + (t >> 4);
      float4 wv = *(const float4*)(W + (size_t)r * CC + ks * 64 + (t & 15) * 4);
      ushort4 pk;
      pk.x = f2h(wv.x); pk.y = f2h(wv.y); pk.z = f2h(wv.z); pk.w = f2h(wv.w);
      *(ushort4*)&u.s.wb[r][(t & 15) * 4] = pk;
    }
    __syncthreads();
#pragma unroll
    for (int kc = 0; kc < 2; ++kc) {
      half8 af[2];
#pragma unroll
      for (int nt = 0; nt < 2; ++nt)
        af[nt] = *(const half8*)&u.s.xa[w * 32 + nt * 16 + l15][kc * 32 + quad * 8];
#pragma unroll
      for (int ct = 0; ct < 16; ++ct) {
        half8 bf = *(const half8*)&u.s.wb[ct * 16 + l15][kc * 32 + quad * 8];
        acc[0][ct] = __builtin_amdgcn_mfma_f32_16x16x32_f16(af[0], bf, acc[0][ct], 0, 0, 0);
        acc[1][ct] = __builtin_amdgcn_mfma_f32_16x16x32_f16(af[1], bf, acc[1][ct], 0, 0, 0);
      }
    }
  }
#pragma unroll
  for (int ct = 0; ct < 16; ++ct) {
    float bv_ = bias[ct * 16 + l15];
#pragma unroll
    for (int nt = 0; nt < 2; ++nt)
#pragma unroll
      for (int r = 0; r < 4; ++r) acc[nt][ct][r] += bv_;
  }
  __syncthreads();
  if (proj < 2) {
#pragma unroll
    for (int nt = 0; nt < 2; ++nt)
#pragma unroll
      for (int ct = 0; ct < 16; ++ct)
#pragma unroll
        for (int r = 0; r < 4; ++r)
          u.qo[w * 32 + nt * 16 + quad * 4 + r][ct * 16 + l15] = f2h(acc[nt][ct][r]);
    __syncthreads();
    unsigned short* out = (proj == 0 ? Q : K) + ((size_t)b * NN + n0) * CC;
#pragma unroll
    for (int p = 0; p < 16; ++p) {
      int f = p * 4096 + t * 16;
      int n = f >> 9, ob = f & 511;
      *(uint4*)((char*)out + (size_t)n * 512 + ob) =
        *(const uint4*)((const char*)&u.qo[n][0] + ob);
    }
  } else {
#pragma unroll
    for (int nt = 0; nt < 2; ++nt)
#pragma unroll
      for (int ct = 0; ct < 16; ++ct)
#pragma unroll
        for (int r = 0; r < 4; ++r)
          u.vo[ct * 16 + l15][w * 32 + nt * 16 + quad * 4 + r] = f2h(acc[nt][ct][r]);
    __syncthreads();
    unsigned short* out = V + (size_t)b * CC * NN + n0;
#pragma unroll
    for (int p = 0; p < 16; ++p) {
      int o = p * 16 + (t >> 4);
      *(uint4*)((char*)out + (size_t)o * NN * 2 + (t & 15) * 16) =
        *(const uint4*)&u.vo[o][(t & 15) * 8];
    }
  }
}

// ---------------- flash attention ----------------
// 256 threads (4 waves), 64 q-rows/block, 2 blocks/CU.
// One 32KB LDS buffer holds the K-tile then the V-tile of each iteration;
// a single 32-VGPR staging array prefetches V (then next-K) behind MFMAs.
// 256-thread blocks are the shape this toolchain grants >128 VGPRs to
// (round 4: 160 granted, zero spill; 512-thread shape hard-capped at 128
// and spilled 470 MB/launch regardless of launch_bounds).
__global__ __launch_bounds__(256, 1) void k_flash(const unsigned short* __restrict__ Q,
    const unsigned short* __restrict__ K, const unsigned short* __restrict__ V,
    float* __restrict__ out, float* __restrict__ opart, float* __restrict__ ml,
    int n_splits) {
  __shared__ union {
    struct {
      unsigned short kv[16384];   // 32KB: K tile (64x256) OR V tile (256x64), swizzled
      unsigned short pt[4096];    // 8KB: 4 waves x 16 q x 64 keys, swizzled
    } s;
    float od[64][68];             // epilogue quarter-tile: [c][q]
  } u;
  int b = blockIdx.y, q0 = blockIdx.x * 64, split = blockIdx.z;
  int nper = 64 / n_splits;
  int t = threadIdx.x, w = t >> 6, lane = t & 63, l15 = lane & 15, quad = lane >> 4;

  // Q fragments in registers (loop-invariant): A[q=l15][c=quad*8+j]
  half8 qf[8];
  const unsigned short* qrow = Q + ((size_t)b * NN + q0 + w * 16 + l15) * CC;
#pragma unroll
  for (int k = 0; k < 8; ++k) qf[k] = *(const half8*)(qrow + k * 32 + quad * 8);

  f32x4 z = {0.f, 0.f, 0.f, 0.f};
  f32x4 o_acc[16];
#pragma unroll
  for (int i = 0; i < 16; ++i) o_acc[i] = z;
  float m_i[4], lp_[4];
#pragma unroll
  for (int r = 0; r < 4; ++r) { m_i[r] = -INFINITY; lp_[r] = 0.f; }

  int it_beg = split * nper, it_end = it_beg + nper;
  uint4 sreg[8];   // shared staging regs: V of current iter, then K of next iter

  // prologue: K tile it_beg -> LDS
  {
    const char* kb = (const char*)(K + ((size_t)b * NN + it_beg * 64) * CC);
#pragma unroll
    for (int p = 0; p < 8; ++p) sreg[p] = *(const uint4*)(kb + p * 4096 + t * 16);
#pragma unroll
    for (int p = 0; p < 8; ++p) {
      int f = p * 4096 + t * 16;
      *(uint4*)&u.s.kv[kt_off(f >> 9, (f >> 4) & 31)] = sreg[p];
    }
  }
  __syncthreads();

  for (int it = it_beg; it < it_end; ++it) {
    // prefetch this iter's V tile into regs (latency hides behind S+softmax)
    {
      const char* vb = (const char*)(V + (size_t)b * CC * NN + it * 64);
#pragma unroll
      for (int p = 0; p < 8; ++p) {
        int f = p * 4096 + t * 16;
        sreg[p] = *(const uint4*)(vb + (size_t)(f >> 7) * 8192 + (f & 127));
      }
    }

    // S = Q K^T : 16 q x 64 keys per wave (kv holds K)
    f32x4 sa[4];
#pragma unroll
    for (int j = 0; j < 4; ++j) sa[j] = z;
#pragma unroll
    for (int k = 0; k < 8; ++k) {
#pragma unroll
      for (int j = 0; j < 4; ++j) {
        half8 bf = *(const half8*)&u.s.kv[kt_off(j * 16 + l15, 4 * k + quad)];
        sa[j] = __builtin_amdgcn_mfma_f32_16x16x32_f16(qf[k], bf, sa[j], 0, 0, 0);
      }
    }
    // online softmax: max butterfly; sum kept per-lane (reduced after loop)
    float mt[4];
#pragma unroll
    for (int r = 0; r < 4; ++r)
      mt[r] = fmaxf(fmaxf(sa[0][r], sa[1][r]), fmaxf(sa[2][r], sa[3][r]));
#pragma unroll
    for (int off = 1; off < 16; off <<= 1)
#pragma unroll
      for (int r = 0; r < 4; ++r)
        mt[r] = fmaxf(mt[r], __shfl_xor(mt[r], off, 64));
    float alpha[4];
#pragma unroll
    for (int r = 0; r < 4; ++r) {
      float mn = fmaxf(m_i[r], mt[r]);
      alpha[r] = __expf(m_i[r] - mn);
      m_i[r] = mn;
    }
#pragma unroll
    for (int r = 0; r < 4; ++r) {
      float ls = 0.f;
#pragma unroll
      for (int j = 0; j < 4; ++j) {
        float p = __expf(sa[j][r] - m_i[r]);
        sa[j][r] = p;
        ls += p;
      }
      lp_[r] = lp_[r] * alpha[r] + ls;
    }
#pragma unroll
    for (int ct = 0; ct < 16; ++ct)
#pragma unroll
      for (int r = 0; r < 4; ++r) o_acc[ct][r] *= alpha[r];
    // P (C/D layout) -> LDS (A-operand layout, within-wave)
#pragma unroll
    for (int j = 0; j < 4; ++j)
#pragma unroll
      for (int r = 0; r < 4; ++r) {
        int row = quad * 4 + r;
        int chunk = 2 * j + (l15 >> 3);
        u.s.pt[w * 1024 + row * 64 + (((chunk ^ row) & 7) << 3) + (l15 & 7)] = f2h(sa[j][r]);
      }

    __syncthreads();   // all waves done reading K from kv
#pragma unroll
    for (int p = 0; p < 8; ++p) {
      int f = p * 4096 + t * 16;
      *(uint4*)&u.s.kv[vt_off(f >> 7, (f >> 4) & 7)] = sreg[p];
    }
    __syncthreads();   // V visible

    // prefetch next iter's K tile into regs (hides behind PV)
    bool has_next = (it + 1 < it_end);
    if (has_next) {
      const char* kb = (const char*)(K + ((size_t)b * NN + (it + 1) * 64) * CC);
#pragma unroll
      for (int p = 0; p < 8; ++p) sreg[p] = *(const uint4*)(kb + p * 4096 + t * 16);
    }

    // O += P @ V^T (kv holds V)
#pragma unroll
    for (int mc = 0; mc < 2; ++mc) {
      half8 af = *(const half8*)&u.s.pt[w * 1024 + l15 * 64 + ((((mc * 4 + quad) ^ l15) & 7) << 3)];
#pragma unroll
      for (int ct = 0; ct < 16; ++ct) {
        half8 bf = *(const half8*)&u.s.kv[vt_off(ct * 16 + l15, mc * 4 + quad)];
        o_acc[ct] = __builtin_amdgcn_mfma_f32_16x16x32_f16(af, bf, o_acc[ct], 0, 0, 0);
      }
    }

    __syncthreads();   // all waves done reading V
    if (has_next) {
#pragma unroll
      for (int p = 0; p < 8; ++p) {
        int f = p * 4096 + t * 16;
        *(uint4*)&u.s.kv[kt_off(f >> 9, (f >> 4) & 31)] = sreg[p];
      }
      __syncthreads();   // next K visible
    }
  }

  // final 16-lane sum reduction of l partials
#pragma unroll
  for (int off = 1; off < 16; off <<= 1)
#pragma unroll
    for (int r = 0; r < 4; ++r)
      lp_[r] += __shfl_xor(lp_[r], off, 64);

  float sc[4];
#pragma unroll
  for (int r = 0; r < 4; ++r) sc[r] = (n_splits == 1) ? 1.f / lp_[r] : 1.f;

  float* ob = (n_splits == 1 ? out : opart + (size_t)split * BB * CC * NN)
              + (size_t)b * CC * NN + q0;
#pragma unroll
  for (int qtr = 0; qtr < 4; ++qtr) {
    __syncthreads();
#pragma unroll
    for (int ct2 = 0; ct2 < 4; ++ct2) {
      int ct = qtr * 4 + ct2;
#pragma unroll
      for (int r = 0; r < 4; ++r)
        u.od[ct2 * 16 + l15][w * 16 + quad * 4 + r] = o_acc[ct][r] * sc[r];
    }
    __syncthreads();
#pragma unroll
    for (int pp = 0; pp < 4; ++pp) {
      int row = pp * 16 + (t >> 4);
      *(float4*)(ob + (size_t)(qtr * 64 + row) * NN + (t & 15) * 4) =
        *(const float4*)&u.od[row][(t & 15) * 4];
    }
  }
  if (n_splits != 1 && l15 == 0) {
    float* mp = ml + ((size_t)(split * 2 + 0) * BB + b) * NN + q0 + w * 16 + quad * 4;
    float* lq = ml + ((size_t)(split * 2 + 1) * BB + b) * NN + q0 + w * 16 + quad * 4;
#pragma unroll
    for (int r = 0; r < 4; ++r) { mp[r] = m_i[r]; lq[r] = lp_[r]; }
  }
}

// ---------------- merge of 2 key-splits ----------------
__global__ __launch_bounds__(256) void k_merge(const float* __restrict__ opart,
    const float* __restrict__ ml, float* __restrict__ out) {
  size_t i = ((size_t)blockIdx.x * 256 + threadIdx.x) * 4;
  int n = (int)(i & (NN - 1));
  int b = (int)(i >> 20);   // i / (CC*NN)
  float4 m1 = *(const float4*)(ml + (size_t)(0 * BB + b) * NN + n);
  float4 l1 = *(const float4*)(ml + (size_t)(1 * BB + b) * NN + n);
  float4 m2 = *(const float4*)(ml + (size_t)(2 * BB + b) * NN + n);
  float4 l2 = *(const float4*)(ml + (size_t)(3 * BB + b) * NN + n);
  float4 o1 = *(const float4*)(opart + i);
  float4 o2 = *(const float4*)(opart + (size_t)BB * CC * NN + i);
  float4 o;
#define MERGE1(f) { \
    float mm = fmaxf(m1.f, m2.f); \
    float e1 = __expf(m1.f - mm), e2 = __expf(m2.f - mm); \
    o.f = (e1 * o1.f + e2 * o2.f) / (e1 * l1.f + e2 * l2.f); }
  MERGE1(x) MERGE1(y) MERGE1(z) MERGE1(w)
#undef MERGE1
  *(float4*)(out + i) = o;
}

extern "C" void kernel_launch(void* const* d_in, const int* in_sizes, int n_in,
                              void* d_out, int out_size, void* d_ws, size_t ws_size,
                              hipStream_t stream) {
  const float* x  = (const float*)d_in[0];
  const float* Wq = (const float*)d_in[1];
  const float* bq = (const float*)d_in[2];
  const float* Wk = (const float*)d_in[3];
  const float* bk = (const float*)d_in[4];
  const float* Wv = (const float*)d_in[5];
  const float* bv = (const float*)d_in[6];
  float* out = (float*)d_out;
  char* ws = (char*)d_ws;
  unsigned short* Xt = (unsigned short*)(ws);
  unsigned short* Qb = (unsigned short*)(ws + (size_t)8  * 1024 * 1024);
  unsigned short* Kb = (unsigned short*)(ws + (size_t)16 * 1024 * 1024);
  unsigned short* Vb = (unsigned short*)(ws + (size_t)24 * 1024 * 1024);
  float* Opart = (float*)(ws + (size_t)32 * 1024 * 1024);  // 2 x 16 MB
  float* Ml    = (float*)(ws + (size_t)64 * 1024 * 1024);  // 4 x 64 KB

  k_transpose<<<dim3(64, 4, 4), 256, 0, stream>>>(x, Xt);
  k_proj<<<dim3(32, 4, 3), 256, 0, stream>>>(Xt, Wq, bq, Wk, bk, Wv, bv, Qb, Kb, Vb);

  bool split2 = ws_size >= (size_t)68 * 1024 * 1024;
  if (split2) {
    k_flash<<<dim3(64, 4, 2), 256, 0, stream>>>(Qb, Kb, Vb, out, Opart, Ml, 2);
    k_merge<<<dim3(4096), 256, 0, stream>>>(Opart, Ml, out);
  } else {
    k_flash<<<dim3(64, 4, 1), 256, 0, stream>>>(Qb, Kb, Vb, out, Opart, Ml, 1);
  }
}

// Round 8
// 219.252 us; speedup vs baseline: 3.7928x; 3.7928x over previous
//
#include <hip/hip_runtime.h>
#include <math.h>

#define BB 4
#define CC 256
#define NN 4096

using half8 = __attribute__((ext_vector_type(8))) _Float16;
using f32x4 = __attribute__((ext_vector_type(4))) float;

__device__ __forceinline__ unsigned short f2h(float f) {
  _Float16 h = (_Float16)f;   // RNE
  return __builtin_bit_cast(unsigned short, h);
}

// async global->LDS DMA, 16B per lane; LDS dest = wave-uniform base + lane*16
#define ASYNC16(g, l)                                                        \
  __builtin_amdgcn_global_load_lds(                                          \
      (const __attribute__((address_space(1))) unsigned int*)(g),            \
      (__attribute__((address_space(3))) unsigned int*)(l), 16, 0, 0)

// XOR bank swizzle at 16B-chunk granularity (applied on the GLOBAL source
// address at DMA time; LDS layout is linear in swizzled-chunk index)
__device__ __forceinline__ int kt_off(int r, int chunk) {   // K view: 64 rows x 512B, short idx
  return r * 256 + (((chunk & 24) | ((chunk ^ r) & 7)) << 3);
}
__device__ __forceinline__ int vt_off(int r, int chunk) {   // V view: 256 rows x 128B, short idx
  return r * 64 + (((chunk ^ r) & 7) << 3);
}

// ---------------- transpose: x (B,C,N) f32 -> Xt (B,N,C) fp16 ----------------
__global__ __launch_bounds__(256) void k_transpose(const float* __restrict__ x,
                                                   unsigned short* __restrict__ Xt) {
  __shared__ float tile[64][65];
  int b = blockIdx.z, c0 = blockIdx.y * 64, n0 = blockIdx.x * 64;
  int t = threadIdx.x;
  const float* xp = x + ((size_t)b * CC + c0) * NN + n0;
#pragma unroll
  for (int p = 0; p < 4; ++p) {
    int c = p * 16 + (t >> 4);
    int j = (t & 15) * 4;
    float4 v = *(const float4*)(xp + (size_t)c * NN + j);
    tile[c][j] = v.x; tile[c][j + 1] = v.y; tile[c][j + 2] = v.z; tile[c][j + 3] = v.w;
  }
  __syncthreads();
  unsigned short* xtp = Xt + ((size_t)b * NN + n0) * CC + c0;
#pragma unroll
  for (int p = 0; p < 2; ++p) {
    int n = p * 32 + (t >> 3);
    int cb = (t & 7) * 8;
    union { unsigned short u[8]; uint4 v; } tmp;
#pragma unroll
    for (int i = 0; i < 8; ++i) tmp.u[i] = f2h(tile[cb + i][n]);
    *(uint4*)(xtp + (size_t)n * CC + cb) = tmp.v;
  }
}

// ---------------- projections ----------------
__global__ __launch_bounds__(256, 1) void k_proj(const unsigned short* __restrict__ Xt,
    const float* __restrict__ Wq, const float* __restrict__ bq,
    const float* __restrict__ Wk, const float* __restrict__ bk,
    const float* __restrict__ Wv, const float* __restrict__ bv,
    unsigned short* __restrict__ Q, unsigned short* __restrict__ K,
    unsigned short* __restrict__ V) {
  __shared__ union {
    struct { unsigned short xa[128][72]; unsigned short wb[256][72]; } s;
    unsigned short qo[128][264];
    unsigned short vo[256][136];
  } u;
  int proj = blockIdx.z;
  const float* W    = proj == 0 ? Wq : (proj == 1 ? Wk : Wv);
  const float* bias = proj == 0 ? bq : (proj == 1 ? bk : bv);
  int b = blockIdx.y, n0 = blockIdx.x * 128;
  int t = threadIdx.x, w = t >> 6, lane = t & 63, l15 = lane & 15, quad = lane >> 4;

  f32x4 z = {0.f, 0.f, 0.f, 0.f};
  f32x4 acc[2][16];
#pragma unroll
  for (int i = 0; i < 2; ++i)
#pragma unroll
    for (int j = 0; j < 16; ++j) acc[i][j] = z;

  for (int ks = 0; ks < 4; ++ks) {
    __syncthreads();
#pragma unroll
    for (int p = 0; p < 4; ++p) {
      int r = p * 32 + (t >> 3);
      *(uint4*)&u.s.xa[r][(t & 7) * 8] =
        *(const uint4*)(Xt + ((size_t)b * NN + n0 + r) * CC + ks * 64 + (t & 7) * 8);
    }
#pragma unroll
    for (int p = 0; p < 16; ++p) {
      int r = p * 16 + (t >> 4);
      float4 wv = *(const float4*)(W + (size_t)r * CC + ks * 64 + (t & 15) * 4);
      ushort4 pk;
      pk.x = f2h(wv.x); pk.y = f2h(wv.y); pk.z = f2h(wv.z); pk.w = f2h(wv.w);
      *(ushort4*)&u.s.wb[r][(t & 15) * 4] = pk;
    }
    __syncthreads();
#pragma unroll
    for (int kc = 0; kc < 2; ++kc) {
      half8 af[2];
#pragma unroll
      for (int nt = 0; nt < 2; ++nt)
        af[nt] = *(const half8*)&u.s.xa[w * 32 + nt * 16 + l15][kc * 32 + quad * 8];
#pragma unroll
      for (int ct = 0; ct < 16; ++ct) {
        half8 bf = *(const half8*)&u.s.wb[ct * 16 + l15][kc * 32 + quad * 8];
        acc[0][ct] = __builtin_amdgcn_mfma_f32_16x16x32_f16(af[0], bf, acc[0][ct], 0, 0, 0);
        acc[1][ct] = __builtin_amdgcn_mfma_f32_16x16x32_f16(af[1], bf, acc[1][ct], 0, 0, 0);
      }
    }
  }
#pragma unroll
  for (int ct = 0; ct < 16; ++ct) {
    float bv_ = bias[ct * 16 + l15];
#pragma unroll
    for (int nt = 0; nt < 2; ++nt)
#pragma unroll
      for (int r = 0; r < 4; ++r) acc[nt][ct][r] += bv_;
  }
  __syncthreads();
  if (proj < 2) {
#pragma unroll
    for (int nt = 0; nt < 2; ++nt)
#pragma unroll
      for (int ct = 0; ct < 16; ++ct)
#pragma unroll
        for (int r = 0; r < 4; ++r)
          u.qo[w * 32 + nt * 16 + quad * 4 + r][ct * 16 + l15] = f2h(acc[nt][ct][r]);
    __syncthreads();
    unsigned short* out = (proj == 0 ? Q : K) + ((size_t)b * NN + n0) * CC;
#pragma unroll
    for (int p = 0; p < 16; ++p) {
      int f = p * 4096 + t * 16;
      int n = f >> 9, ob = f & 511;
      *(uint4*)((char*)out + (size_t)n * 512 + ob) =
        *(const uint4*)((const char*)&u.qo[n][0] + ob);
    }
  } else {
#pragma unroll
    for (int nt = 0; nt < 2; ++nt)
#pragma unroll
      for (int ct = 0; ct < 16; ++ct)
#pragma unroll
        for (int r = 0; r < 4; ++r)
          u.vo[ct * 16 + l15][w * 32 + nt * 16 + quad * 4 + r] = f2h(acc[nt][ct][r]);
    __syncthreads();
    unsigned short* out = V + (size_t)b * CC * NN + n0;
#pragma unroll
    for (int p = 0; p < 16; ++p) {
      int o = p * 16 + (t >> 4);
      *(uint4*)((char*)out + (size_t)o * NN * 2 + (t & 15) * 16) =
        *(const uint4*)&u.vo[o][(t & 15) * 8];
    }
  }
}

// ---------------- flash attention ----------------
// 512 threads (8 waves, the shape that reliably gives 8 waves/CU — measured
// 24% occ in r5/6; two 256-thread blocks never co-schedule, r4/r7 ~12%).
// VGPR cap at 512 threads is 128 (measured r5/r6); the live set fits only
// because staging goes via global_load_lds DMA (no staging VGPRs).
// K/V double-buffered as four SEPARATE __shared__ arrays; the K-loop is
// unrolled x2 with hard-coded buffer pointers so the compiler can prove the
// current iteration's ds_reads never alias the in-flight DMA destination
// (no conservative vmcnt waits inside compute; single barrier per iter).
__global__ __launch_bounds__(512) void k_flash(const unsigned short* __restrict__ Q,
    const unsigned short* __restrict__ K, const unsigned short* __restrict__ V,
    float* __restrict__ out, float* __restrict__ opart, float* __restrict__ ml,
    int n_splits) {
  __shared__ unsigned short ktA[16384], ktB[16384];   // 32KB each: 64 keys x 256 c
  __shared__ unsigned short vtA[16384], vtB[16384];   // 32KB each: 256 c x 64 keys
  __shared__ unsigned short pt[8192];                 // 16KB: 8 waves x 16q x 64k
  int b = blockIdx.y, q0 = blockIdx.x * 128, split = blockIdx.z;
  int nper = 64 / n_splits;
  int t = threadIdx.x, w = t >> 6, lane = t & 63, l15 = lane & 15, quad = lane >> 4;

  // Q fragments in registers (loop-invariant): A[q=l15][c=quad*8+j]
  half8 qf[8];
  const unsigned short* qrow = Q + ((size_t)b * NN + q0 + w * 16 + l15) * CC;
#pragma unroll
  for (int k = 0; k < 8; ++k) qf[k] = *(const half8*)(qrow + k * 32 + quad * 8);

  f32x4 z = {0.f, 0.f, 0.f, 0.f};
  f32x4 o_acc[16];
#pragma unroll
  for (int i = 0; i < 16; ++i) o_acc[i] = z;
  float m_i[4], lp_[4];
#pragma unroll
  for (int r = 0; r < 4; ++r) { m_i[r] = -INFINITY; lp_[r] = 0.f; }

  int it_beg = split * nper, it_end = it_beg + nper;

  // DMA a 32KB K tile: lane handles swizzled chunk c_lds = p*512+t; the
  // inverse swizzle is applied to the global source offset.
  auto dma_k = [&](int it, unsigned short* dst) {
    const char* kb = (const char*)(K + ((size_t)b * NN + it * 64) * CC);
#pragma unroll
    for (int p = 0; p < 4; ++p) {
      int c = p * 512 + t;
      int r = c >> 5, lo = c & 31;
      int chunk = (lo & 24) | ((lo ^ r) & 7);
      ASYNC16(kb + r * 512 + chunk * 16, &dst[(p * 512 + (w << 6)) * 8]);
    }
  };
  auto dma_v = [&](int it, unsigned short* dst) {
    const char* vb = (const char*)(V + (size_t)b * CC * NN + it * 64);
#pragma unroll
    for (int p = 0; p < 4; ++p) {
      int c = p * 512 + t;
      int r = c >> 3;
      int chunk = (c ^ r) & 7;
      ASYNC16(vb + (size_t)r * 8192 + chunk * 16, &dst[(p * 512 + (w << 6)) * 8]);
    }
  };

  auto body = [&](const unsigned short* ktc, const unsigned short* vtc,
                  unsigned short* ktn, unsigned short* vtn, int it) {
    if (it + 1 < it_end) { dma_k(it + 1, ktn); dma_v(it + 1, vtn); }

    // S = Q K^T : 16 q x 64 keys per wave
    f32x4 sa[4];
#pragma unroll
    for (int j = 0; j < 4; ++j) sa[j] = z;
#pragma unroll
    for (int k = 0; k < 8; ++k) {
#pragma unroll
      for (int j = 0; j < 4; ++j) {
        half8 bf = *(const half8*)&ktc[kt_off(j * 16 + l15, 4 * k + quad)];
        sa[j] = __builtin_amdgcn_mfma_f32_16x16x32_f16(qf[k], bf, sa[j], 0, 0, 0);
      }
    }
    // online softmax: max butterfly; sum kept per-lane (reduced after loop)
    float mt[4];
#pragma unroll
    for (int r = 0; r < 4; ++r)
      mt[r] = fmaxf(fmaxf(sa[0][r], sa[1][r]), fmaxf(sa[2][r], sa[3][r]));
#pragma unroll
    for (int off = 1; off < 16; off <<= 1)
#pragma unroll
      for (int r = 0; r < 4; ++r)
        mt[r] = fmaxf(mt[r], __shfl_xor(mt[r], off, 64));
    float alpha[4];
#pragma unroll
    for (int r = 0; r < 4; ++r) {
      float mn = fmaxf(m_i[r], mt[r]);
      alpha[r] = __expf(m_i[r] - mn);
      m_i[r] = mn;
    }
#pragma unroll
    for (int r = 0; r < 4; ++r) {
      float ls = 0.f;
#pragma unroll
      for (int j = 0; j < 4; ++j) {
        float p = __expf(sa[j][r] - m_i[r]);
        sa[j][r] = p;
        ls += p;
      }
      lp_[r] = lp_[r] * alpha[r] + ls;
    }
#pragma unroll
    for (int ct = 0; ct < 16; ++ct)
#pragma unroll
      for (int r = 0; r < 4; ++r) o_acc[ct][r] *= alpha[r];
    // P (C/D layout) -> per-wave LDS scratch (A-operand layout, same-wave RAW)
#pragma unroll
    for (int j = 0; j < 4; ++j)
#pragma unroll
      for (int r = 0; r < 4; ++r) {
        int row = quad * 4 + r;
        int chunk = 2 * j + (l15 >> 3);
        pt[w * 1024 + row * 64 + (((chunk ^ row) & 7) << 3) + (l15 & 7)] = f2h(sa[j][r]);
      }
    // O += P @ V^T
#pragma unroll
    for (int mc = 0; mc < 2; ++mc) {
      half8 af = *(const half8*)&pt[w * 1024 + l15 * 64 + ((((mc * 4 + quad) ^ l15) & 7) << 3)];
#pragma unroll
      for (int ct = 0; ct < 16; ++ct) {
        half8 bf = *(const half8*)&vtc[vt_off(ct * 16 + l15, mc * 4 + quad)];
        o_acc[ct] = __builtin_amdgcn_mfma_f32_16x16x32_f16(af, bf, o_acc[ct], 0, 0, 0);
      }
    }
    __syncthreads();   // drains DMA (next bufs ready) + all waves done with cur
  };

  // prologue: DMA first tile into A buffers
  dma_k(it_beg, ktA);
  dma_v(it_beg, vtA);
  __syncthreads();

  for (int it = it_beg; it < it_end; it += 2) {   // nper is even (64 or 32)
    body(ktA, vtA, ktB, vtB, it);
    body(ktB, vtB, ktA, vtA, it + 1);
  }

  // final 16-lane sum reduction of l partials
#pragma unroll
  for (int off = 1; off < 16; off <<= 1)
#pragma unroll
    for (int r = 0; r < 4; ++r)
      lp_[r] += __shfl_xor(lp_[r], off, 64);

  float sc[4];
#pragma unroll
  for (int r = 0; r < 4; ++r) sc[r] = (n_splits == 1) ? 1.f / lp_[r] : 1.f;

  // epilogue: stage O via ktA reinterpreted as [64][128] f32, 4 quarters
  float (*od)[128] = (float(*)[128])ktA;
  float* ob = (n_splits == 1 ? out : opart + (size_t)split * BB * CC * NN)
              + (size_t)b * CC * NN + q0;
#pragma unroll
  for (int qtr = 0; qtr < 4; ++qtr) {
    __syncthreads();
#pragma unroll
    for (int ct2 = 0; ct2 < 4; ++ct2) {
      int ct = qtr * 4 + ct2;
#pragma unroll
      for (int r = 0; r < 4; ++r)
        od[ct2 * 16 + l15][w * 16 + quad * 4 + r] = o_acc[ct][r] * sc[r];
    }
    __syncthreads();
#pragma unroll
    for (int pp = 0; pp < 4; ++pp) {
      int row = pp * 16 + (t >> 5);
      *(float4*)(ob + (size_t)(qtr * 64 + row) * NN + (t & 31) * 4) =
        *(const float4*)&od[row][(t & 31) * 4];
    }
  }
  if (n_splits != 1 && l15 == 0) {
    float* mp = ml + ((size_t)(split * 2 + 0) * BB + b) * NN + q0 + w * 16 + quad * 4;
    float* lq = ml + ((size_t)(split * 2 + 1) * BB + b) * NN + q0 + w * 16 + quad * 4;
#pragma unroll
    for (int r = 0; r < 4; ++r) { mp[r] = m_i[r]; lq[r] = lp_[r]; }
  }
}

// ---------------- merge of 2 key-splits ----------------
__global__ __launch_bounds__(256) void k_merge(const float* __restrict__ opart,
    const float* __restrict__ ml, float* __restrict__ out) {
  size_t i = ((size_t)blockIdx.x * 256 + threadIdx.x) * 4;
  int n = (int)(i & (NN - 1));
  int b = (int)(i >> 20);   // i / (CC*NN)
  float4 m1 = *(const float4*)(ml + (size_t)(0 * BB + b) * NN + n);
  float4 l1 = *(const float4*)(ml + (size_t)(1 * BB + b) * NN + n);
  float4 m2 = *(const float4*)(ml + (size_t)(2 * BB + b) * NN + n);
  float4 l2 = *(const float4*)(ml + (size_t)(3 * BB + b) * NN + n);
  float4 o1 = *(const float4*)(opart + i);
  float4 o2 = *(const float4*)(opart + (size_t)BB * CC * NN + i);
  float4 o;
#define MERGE1(f) { \
    float mm = fmaxf(m1.f, m2.f); \
    float e1 = __expf(m1.f - mm), e2 = __expf(m2.f - mm); \
    o.f = (e1 * o1.f + e2 * o2.f) / (e1 * l1.f + e2 * l2.f); }
  MERGE1(x) MERGE1(y) MERGE1(z) MERGE1(w)
#undef MERGE1
  *(float4*)(out + i) = o;
}

extern "C" void kernel_launch(void* const* d_in, const int* in_sizes, int n_in,
                              void* d_out, int out_size, void* d_ws, size_t ws_size,
                              hipStream_t stream) {
  const float* x  = (const float*)d_in[0];
  const float* Wq = (const float*)d_in[1];
  const float* bq = (const float*)d_in[2];
  const float* Wk = (const float*)d_in[3];
  const float* bk = (const float*)d_in[4];
  const float* Wv = (const float*)d_in[5];
  const float* bv = (const float*)d_in[6];
  float* out = (float*)d_out;
  char* ws = (char*)d_ws;
  unsigned short* Xt = (unsigned short*)(ws);
  unsigned short* Qb = (unsigned short*)(ws + (size_t)8  * 1024 * 1024);
  unsigned short* Kb = (unsigned short*)(ws + (size_t)16 * 1024 * 1024);
  unsigned short* Vb = (unsigned short*)(ws + (size_t)24 * 1024 * 1024);
  float* Opart = (float*)(ws + (size_t)32 * 1024 * 1024);  // 2 x 16 MB
  float* Ml    = (float*)(ws + (size_t)64 * 1024 * 1024);  // 4 x 64 KB

  k_transpose<<<dim3(64, 4, 4), 256, 0, stream>>>(x, Xt);
  k_proj<<<dim3(32, 4, 3), 256, 0, stream>>>(Xt, Wq, bq, Wk, bk, Wv, bv, Qb, Kb, Vb);

  bool split2 = ws_size >= (size_t)68 * 1024 * 1024;
  if (split2) {
    k_flash<<<dim3(32, 4, 2), 512, 0, stream>>>(Qb, Kb, Vb, out, Opart, Ml, 2);
    k_merge<<<dim3(4096), 256, 0, stream>>>(Opart, Ml, out);
  } else {
    k_flash<<<dim3(32, 4, 1), 512, 0, stream>>>(Qb, Kb, Vb, out, Opart, Ml, 1);
  }
}